// Round 4
// baseline (43.735 us; speedup 1.0000x reference)
//
#include <hip/hip_runtime.h>
#include <hip/hip_cooperative_groups.h>

namespace cg = cooperative_groups;

#define BATCH 4
#define IMH 96
#define IMW 96
#define NPIX (IMH * IMW)          // 9216
#define CHUNKS (NPIX / 256)       // 36 blocks per image
#define NBLK (BATCH * CHUNKS)     // 144

// --- Single cooperative kernel: per-pixel dice/focal stats + exact
//     nearest-target d^2 (5x5 window, ring fallback), block partials to ws,
//     grid.sync(), block 0 combines everything into the scalar loss.
//     grid = NBLK x 256, 1 thread : 1 pixel ---
__global__ void __launch_bounds__(256) combined_kernel(const float* __restrict__ pred,
                                                       const float* __restrict__ target,
                                                       float* __restrict__ ws,
                                                       float* __restrict__ out) {
    __shared__ float smem[4][8];
    int blk   = blockIdx.x;
    int b     = blk / CHUNKS;
    int chunk = blk - b * CHUNKS;
    const float* p = pred + b * NPIX;
    const float* t = target + b * NPIX;

    int i  = chunk * 256 + (int)threadIdx.x;
    int py = i / IMW, px = i - py * IMW;
    float pv = p[i];

    // ---- one-shot 5x5 neighborhood load (OOB -> 0), all loads independent ----
    float w[5][5];
    #pragma unroll
    for (int dy = -2; dy <= 2; ++dy) {
        int yy = py + dy;
        bool yok = (unsigned)yy < (unsigned)IMH;
        #pragma unroll
        for (int dx = -2; dx <= 2; ++dx) {
            int xx = px + dx;
            bool ok = yok && ((unsigned)xx < (unsigned)IMW);
            w[dy + 2][dx + 2] = ok ? t[yy * IMW + xx] : 0.f;
        }
    }
    float tv = w[2][2];

    // 3x3 Laplacian from window registers (zero SAME padding matches OOB=0)
    float lap = w[1][2] + w[3][2] + w[2][1] + w[2][3] - 4.f * tv;
    float em  = (lap != 0.f) ? 1.f : 0.f;

    float prob = 1.f / (1.f + expf(-pv));
    float ce = fmaxf(pv, 0.f) - pv * tv + log1pf(expf(-fabsf(pv)));
    float pt = prob * tv + (1.f - prob) * (1.f - tv);
    float om = 1.f - pt;
    float fsum = (1.f + 3.f * em) * (0.25f * om * om * ce);

    // ---- nearest-target squared distance: window min, then rare fallback ----
    // 5x5 covers d^2<=8; ring-3 min d^2 is 9, so __all(best<=9) proves exact.
    int best = 0x7fffffff;
    #pragma unroll
    for (int dy = -2; dy <= 2; ++dy)
        #pragma unroll
        for (int dx = -2; dx <= 2; ++dx)
            if (w[dy + 2][dx + 2] > 0.5f) best = min(best, dy * dy + dx * dx);

    if (!__all(best <= 9)) {               // cold path: P ~= 64 * 2^-25 per wave
        for (int r = 3; r <= 95; ++r) {
            int rr = r * r;
            if (__all(best <= rr)) break;
            if (best > rr) {
                int y0 = py - r, y1 = py + r, x0 = px - r, x1 = px + r;
                for (int xx = x0; xx <= x1; ++xx) {
                    if ((unsigned)xx < (unsigned)IMW) {
                        int dx = xx - px, dd = dx * dx + rr;
                        if ((unsigned)y0 < (unsigned)IMH && t[y0 * IMW + xx] > 0.5f) best = min(best, dd);
                        if ((unsigned)y1 < (unsigned)IMH && t[y1 * IMW + xx] > 0.5f) best = min(best, dd);
                    }
                }
                for (int yy = y0 + 1; yy <= y1 - 1; ++yy) {
                    if ((unsigned)yy < (unsigned)IMH) {
                        int dy = yy - py, dd = dy * dy + rr;
                        if ((unsigned)x0 < (unsigned)IMW && t[yy * IMW + x0] > 0.5f) best = min(best, dd);
                        if ((unsigned)x1 < (unsigned)IMW && t[yy * IMW + x1] > 0.5f) best = min(best, dd);
                    }
                }
            }
        }
    }
    // no-target image => best stays INT_MAX => contributes 0 (matches where(m.any(),...))
    float hd_val = (best == 0x7fffffff) ? 0.f : pv * (float)best;

    // ---- packed 7-way block reduction: 6 shuffle rounds + ONE barrier ----
    float vals[7] = { prob * tv, prob, tv, prob * em, em, fsum, hd_val };
    int lane = threadIdx.x & 63;
    int wid  = threadIdx.x >> 6;
    #pragma unroll
    for (int o = 32; o > 0; o >>= 1) {
        #pragma unroll
        for (int k = 0; k < 7; ++k) vals[k] += __shfl_down(vals[k], o, 64);
    }
    if (lane == 0) {
        #pragma unroll
        for (int k = 0; k < 7; ++k) smem[wid][k] = vals[k];
    }
    __syncthreads();
    if (threadIdx.x == 0) {
        float* wsb = ws + blk * 8;
        #pragma unroll
        for (int k = 0; k < 7; ++k)
            wsb[k] = smem[0][k] + smem[1][k] + smem[2][k] + smem[3][k];
    }

    // ---- grid-wide barrier, then block 0 finalizes ----
    __threadfence();                 // device-scope: partials visible cross-XCD
    cg::this_grid().sync();

    if (blk == 0) {
        __shared__ float simg[BATCH][8];
        int tid = (int)threadIdx.x;
        int iw  = tid >> 6;          // image index
        int iln = tid & 63;
        float v[7] = {0.f, 0.f, 0.f, 0.f, 0.f, 0.f, 0.f};
        if (iln < CHUNKS) {
            const float* wsb = ws + (iw * CHUNKS + iln) * 8;
            #pragma unroll
            for (int k = 0; k < 7; ++k) v[k] = wsb[k];
        }
        #pragma unroll
        for (int o = 32; o > 0; o >>= 1) {
            #pragma unroll
            for (int k = 0; k < 7; ++k) v[k] += __shfl_down(v[k], o, 64);
        }
        if (iln == 0) {
            #pragma unroll
            for (int k = 0; k < 7; ++k) simg[iw][k] = v[k];
        }
        __syncthreads();
        if (tid == 0) {
            float dice_all_sum = 0.f, dice_e_sum = 0.f, te_total = 0.f, fs = 0.f, hd = 0.f;
            for (int bb = 0; bb < BATCH; ++bb) {
                float inter   = simg[bb][0];
                float psum    = simg[bb][1];
                float tsum    = simg[bb][2];
                float inter_e = simg[bb][3];
                float tesum   = simg[bb][4];
                fs += simg[bb][5];
                hd += simg[bb][6];
                dice_all_sum += (2.f * inter + 1e-5f) / (psum + tsum + 1e-5f);
                dice_e_sum   += (2.f * inter_e + 1e-5f) / (inter_e + tesum + 1e-5f);
                te_total += tesum;
            }
            float loss_all  = 1.f - dice_all_sum * 0.25f;
            float loss_edge = (te_total > 0.f) ? (1.f - dice_e_sum * 0.25f) : 0.f;
            float dice_loss = loss_all + 2.0f * loss_edge;
            float focal_loss = fs / (float)(BATCH * NPIX);
            float hd_loss = hd * 0.25f;
            out[0] = 1.0f * dice_loss + 0.5f * focal_loss + 0.1f * hd_loss;
        }
    }
}

extern "C" void kernel_launch(void* const* d_in, const int* in_sizes, int n_in,
                              void* d_out, int out_size, void* d_ws, size_t ws_size,
                              hipStream_t stream) {
    const float* pred   = (const float*)d_in[0];
    const float* target = (const float*)d_in[1];
    float* out = (float*)d_out;
    float* ws  = (float*)d_ws;   // needs NBLK*8 floats = 4608 B

    void* args[] = { (void*)&pred, (void*)&target, (void*)&ws, (void*)&out };
    hipLaunchCooperativeKernel((const void*)combined_kernel, dim3(NBLK), dim3(256),
                               args, 0, stream);
}

// Round 5
// 12.812 us; speedup vs baseline: 3.4136x; 3.4136x over previous
//
#include <hip/hip_runtime.h>

#define BATCH 4
#define IMH 96
#define IMW 96
#define NPIX (IMH * IMW)          // 9216
#define CHUNKS (NPIX / 256)       // 36 blocks per image
#define NBLK (BATCH * CHUNKS)     // 144

// --- Fused per-pixel kernel: dice/focal stats + exact nearest-target d^2.
//     5x5 window covers d^2<=8; ring-3 min d^2 is 9, so __all(best<=9) proves
//     exactness. Generic ring fallback kept for the 2^-25 case / no-target.
//     grid = NBLK x 256, 1 thread : 1 pixel ---
__global__ void __launch_bounds__(256) fused_kernel(const float* __restrict__ pred,
                                                    const float* __restrict__ target,
                                                    float* __restrict__ ws) {
    __shared__ float smem[4][8];
    int blk   = blockIdx.x;
    int b     = blk / CHUNKS;
    int chunk = blk - b * CHUNKS;
    const float* p = pred + b * NPIX;
    const float* t = target + b * NPIX;

    int i  = chunk * 256 + (int)threadIdx.x;
    int py = i / IMW, px = i - py * IMW;
    float pv = p[i];

    // ---- one-shot 5x5 neighborhood load (OOB -> 0), all loads independent ----
    float w[5][5];
    #pragma unroll
    for (int dy = -2; dy <= 2; ++dy) {
        int yy = py + dy;
        bool yok = (unsigned)yy < (unsigned)IMH;
        #pragma unroll
        for (int dx = -2; dx <= 2; ++dx) {
            int xx = px + dx;
            bool ok = yok && ((unsigned)xx < (unsigned)IMW);
            w[dy + 2][dx + 2] = ok ? t[yy * IMW + xx] : 0.f;
        }
    }
    float tv = w[2][2];

    // 3x3 Laplacian from window registers (zero SAME padding matches OOB=0)
    float lap = w[1][2] + w[3][2] + w[2][1] + w[2][3] - 4.f * tv;
    float em  = (lap != 0.f) ? 1.f : 0.f;

    float prob = 1.f / (1.f + expf(-pv));
    float ce = fmaxf(pv, 0.f) - pv * tv + log1pf(expf(-fabsf(pv)));
    float pt = prob * tv + (1.f - prob) * (1.f - tv);
    float om = 1.f - pt;
    float fsum = (1.f + 3.f * em) * (0.25f * om * om * ce);

    // ---- nearest-target squared distance: window min, then rare fallback ----
    int best = 0x7fffffff;
    #pragma unroll
    for (int dy = -2; dy <= 2; ++dy)
        #pragma unroll
        for (int dx = -2; dx <= 2; ++dx)
            if (w[dy + 2][dx + 2] > 0.5f) best = min(best, dy * dy + dx * dx);

    if (!__all(best <= 9)) {               // cold path: P ~= 64 * 2^-25 per wave
        for (int r = 3; r <= 95; ++r) {
            int rr = r * r;
            if (__all(best <= rr)) break;
            if (best > rr) {
                int y0 = py - r, y1 = py + r, x0 = px - r, x1 = px + r;
                for (int xx = x0; xx <= x1; ++xx) {
                    if ((unsigned)xx < (unsigned)IMW) {
                        int dx = xx - px, dd = dx * dx + rr;
                        if ((unsigned)y0 < (unsigned)IMH && t[y0 * IMW + xx] > 0.5f) best = min(best, dd);
                        if ((unsigned)y1 < (unsigned)IMH && t[y1 * IMW + xx] > 0.5f) best = min(best, dd);
                    }
                }
                for (int yy = y0 + 1; yy <= y1 - 1; ++yy) {
                    if ((unsigned)yy < (unsigned)IMH) {
                        int dy = yy - py, dd = dy * dy + rr;
                        if ((unsigned)x0 < (unsigned)IMW && t[yy * IMW + x0] > 0.5f) best = min(best, dd);
                        if ((unsigned)x1 < (unsigned)IMW && t[yy * IMW + x1] > 0.5f) best = min(best, dd);
                    }
                }
            }
        }
    }
    // no-target image => best stays INT_MAX => contributes 0 (matches where(m.any(),...))
    float hd_val = (best == 0x7fffffff) ? 0.f : pv * (float)best;

    // ---- packed 7-way block reduction: 6 shuffle rounds + ONE barrier ----
    float vals[7] = { prob * tv, prob, tv, prob * em, em, fsum, hd_val };
    int lane = threadIdx.x & 63;
    int wid  = threadIdx.x >> 6;
    #pragma unroll
    for (int o = 32; o > 0; o >>= 1) {
        #pragma unroll
        for (int k = 0; k < 7; ++k) vals[k] += __shfl_down(vals[k], o, 64);
    }
    if (lane == 0) {
        #pragma unroll
        for (int k = 0; k < 7; ++k) smem[wid][k] = vals[k];
    }
    __syncthreads();
    if (threadIdx.x == 0) {
        float* wsb = ws + blk * 8;
        #pragma unroll
        for (int k = 0; k < 7; ++k)
            wsb[k] = smem[0][k] + smem[1][k] + smem[2][k] + smem[3][k];
    }
}

// --- Finalize: wave w reduces image w's 36 block-partials; thread 0 combines ---
__global__ void __launch_bounds__(256) finalize_kernel(const float* __restrict__ ws,
                                                       float* __restrict__ out) {
    __shared__ float simg[BATCH][8];
    int tid  = threadIdx.x;
    int wid  = tid >> 6;       // image index
    int lane = tid & 63;
    float v[7] = {0.f, 0.f, 0.f, 0.f, 0.f, 0.f, 0.f};
    if (lane < CHUNKS) {
        const float* w = ws + (wid * CHUNKS + lane) * 8;
        #pragma unroll
        for (int k = 0; k < 7; ++k) v[k] = w[k];
    }
    #pragma unroll
    for (int o = 32; o > 0; o >>= 1) {
        #pragma unroll
        for (int k = 0; k < 7; ++k) v[k] += __shfl_down(v[k], o, 64);
    }
    if (lane == 0) {
        #pragma unroll
        for (int k = 0; k < 7; ++k) simg[wid][k] = v[k];
    }
    __syncthreads();
    if (tid == 0) {
        float dice_all_sum = 0.f, dice_e_sum = 0.f, te_total = 0.f, fsum = 0.f, hd = 0.f;
        for (int b = 0; b < BATCH; ++b) {
            float inter   = simg[b][0];
            float psum    = simg[b][1];
            float tsum    = simg[b][2];
            float inter_e = simg[b][3];
            float tesum   = simg[b][4];
            fsum += simg[b][5];
            hd   += simg[b][6];
            dice_all_sum += (2.f * inter + 1e-5f) / (psum + tsum + 1e-5f);
            dice_e_sum   += (2.f * inter_e + 1e-5f) / (inter_e + tesum + 1e-5f);
            te_total += tesum;
        }
        float loss_all  = 1.f - dice_all_sum * 0.25f;
        float loss_edge = (te_total > 0.f) ? (1.f - dice_e_sum * 0.25f) : 0.f;
        float dice_loss = loss_all + 2.0f * loss_edge;
        float focal_loss = fsum / (float)(BATCH * NPIX);
        float hd_loss = hd * 0.25f;
        out[0] = 1.0f * dice_loss + 0.5f * focal_loss + 0.1f * hd_loss;
    }
}

extern "C" void kernel_launch(void* const* d_in, const int* in_sizes, int n_in,
                              void* d_out, int out_size, void* d_ws, size_t ws_size,
                              hipStream_t stream) {
    const float* pred   = (const float*)d_in[0];
    const float* target = (const float*)d_in[1];
    float* out = (float*)d_out;
    float* ws  = (float*)d_ws;   // needs NBLK*8 floats = 4608 B

    hipLaunchKernelGGL(fused_kernel,    dim3(NBLK), dim3(256), 0, stream, pred, target, ws);
    hipLaunchKernelGGL(finalize_kernel, dim3(1),    dim3(256), 0, stream, ws, out);
}